// Round 7
// baseline (648.335 us; speedup 1.0000x reference)
//
#include <hip/hip_runtime.h>

// ---------- static device workspace ----------
static __device__ __align__(256) unsigned char g_ws[645200000];

// ---------- types ----------
typedef __attribute__((ext_vector_type(8))) __bf16 bf16x8;
typedef __attribute__((ext_vector_type(4))) float  f32x4;
typedef __attribute__((ext_vector_type(8))) unsigned short u16x8;

__device__ __forceinline__ short f2bf(float f) {
    union { float f; unsigned u; } v; v.f = f;
    unsigned r = v.u + 0x7FFFu + ((v.u >> 16) & 1u);
    return (short)(r >> 16);
}
__device__ __forceinline__ float bf2f(unsigned short u) {
    union { unsigned u; float f; } v; v.u = ((unsigned)u) << 16;
    return v.f;
}
__device__ __forceinline__ float elu1(float x) {
    return x > 0.f ? x + 1.f : __expf(x);
}
__device__ __forceinline__ void gload_lds16(const void* g, void* l) {
    __builtin_amdgcn_global_load_lds(
        (const __attribute__((address_space(1))) unsigned int*)g,
        (__attribute__((address_space(3))) unsigned int*)l, 16, 0, 0);
}

#define MFMA16(a, b, c) __builtin_amdgcn_mfma_f32_16x16x32_bf16((a), (b), (c), 0, 0, 0)

// ---------- fp32 -> bf16 convert ----------
__global__ __launch_bounds__(256) void cvt_bf16(
    const float* __restrict__ src, short* __restrict__ dst, int n)
{
    const int i = (blockIdx.x * 256 + threadIdx.x) * 4;
    if (i < n) {
        const float4 v = *(const float4*)(src + i);
        ushort4 o;
        o.x = (unsigned short)f2bf(v.x);
        o.y = (unsigned short)f2bf(v.y);
        o.z = (unsigned short)f2bf(v.z);
        o.w = (unsigned short)f2bf(v.w);
        *(ushort4*)(dst + i) = o;
    }
}

// ---------- GEMM 256x128, BK=64, 3-slot single-barrier pipeline ----------
// C = A(bf16[M][lda]) @ Bt(bf16[Npad][ldb])^T.  512 thr (8 waves, 4Mx2N).
// grid = (M/256)*(Npad/128), row-major tiles: col = id%nby, row = id/nby.
// K mult of 64.  LDS rows 128B; swizzle byte ^= ((row&7)<<4) via pre-permuted
// global source (linear gload_lds dest) + same XOR on ds_read. 0 conflicts.
// EPI: 0=f32 plain, 1=bf16 plain, 2=q-mode (rope+elu+[b,h,s,192]), 3=kv-mode.
template <int EPI>
__global__ __launch_bounds__(512, 1) void gemm_bn(
    const short* __restrict__ A, int lda,
    const short* __restrict__ Bt, int ldb,
    void* __restrict__ C0, void* __restrict__ C1, int ldc,
    int Nvalid, int K, int nby,
    const float* __restrict__ cosT, const float* __restrict__ sinT)
{
    __shared__ char lds[147456];   // A: 3 slots x 32K at 0; B: 3 slots x 16K at 98304
    const int t = threadIdx.x;
    const int lane = t & 63, w = t >> 6;

    // XCD chunking (grid % 8 == 0 at all call sites); row-major tiles inside.
    const int cpx = gridDim.x >> 3;
    const int id = ((int)blockIdx.x & 7) * cpx + ((int)blockIdx.x >> 3);
    const int col0 = (id % nby) * 128;
    const int row0 = (id / nby) * 256;

    // staging: A wave w -> rows [w*32,w*32+32) (4 issues); B -> rows [w*16,w*16+16) (2 issues)
    const int r8 = lane >> 3;
    const int srcb = ((lane & 7) ^ r8) << 4;      // pre-permuted source byte
    const char* aSrc = (const char*)A + ((size_t)(row0 + w * 32 + r8) * lda) * 2 + srcb;
    const char* bSrc = (const char*)Bt + ((size_t)(col0 + w * 16 + r8) * ldb) * 2 + srcb;
    const size_t aRow8 = (size_t)lda * 16;        // 8 rows in bytes
    const size_t bRow8 = (size_t)ldb * 16;
    char* aD = lds + w * 4096 + lane * 16;
    char* bD = lds + 98304 + w * 2048 + lane * 16;

    // compute: wave grid 4(M)x2(N); per-wave 64x64 out
    const int wr = (w >> 1) * 64, wc = (w & 1) * 64;
    const int l15 = lane & 15;
    const int g16 = (lane >> 4) * 16;
    const int rxor = (l15 & 7) << 4;

    const int NT = K >> 6;

    auto STAGE = [&](int j) {
        const int sl = j % 3;
        const size_t kb = (size_t)j * 128;
#pragma unroll
        for (int p = 0; p < 4; ++p)
            gload_lds16(aSrc + kb + p * aRow8, aD + sl * 32768 + p * 1024);
#pragma unroll
        for (int p = 0; p < 2; ++p)
            gload_lds16(bSrc + kb + p * bRow8, bD + sl * 16384 + p * 1024);
    };

    f32x4 acc[4][4];
#pragma unroll
    for (int i = 0; i < 4; ++i)
#pragma unroll
        for (int j = 0; j < 4; ++j) acc[i][j] = (f32x4){0.f, 0.f, 0.f, 0.f};

    STAGE(0); STAGE(1);

#pragma unroll 1
    for (int kt = 0; kt < NT; ++kt) {
        if (kt + 1 < NT) asm volatile("s_waitcnt vmcnt(6)" ::: "memory");
        else             asm volatile("s_waitcnt vmcnt(0)" ::: "memory");
        __builtin_amdgcn_sched_barrier(0);
        __builtin_amdgcn_s_barrier();
        if (kt + 2 < NT) STAGE(kt + 2);     // writes slot (kt+2)%3 == previous iter's slot
        const char* aS = lds + (kt % 3) * 32768;
        const char* bS = lds + 98304 + (kt % 3) * 16384;
#pragma unroll
        for (int half = 0; half < 2; ++half) {
            const int ko = half * 64;
            bf16x8 af[4], bf4[4];
#pragma unroll
            for (int i = 0; i < 4; ++i)
                af[i] = *(const bf16x8*)(aS + (wr + i * 16 + l15) * 128 + ((ko + g16) ^ rxor));
#pragma unroll
            for (int j = 0; j < 4; ++j)
                bf4[j] = *(const bf16x8*)(bS + (wc + j * 16 + l15) * 128 + ((ko + g16) ^ rxor));
            __builtin_amdgcn_s_setprio(1);
#pragma unroll
            for (int i = 0; i < 4; ++i)
#pragma unroll
                for (int j = 0; j < 4; ++j)
                    acc[i][j] = MFMA16(af[i], bf4[j], acc[i][j]);
            __builtin_amdgcn_s_setprio(0);
        }
    }

    const int rbase = (lane >> 4) * 4;
#pragma unroll
    for (int i = 0; i < 4; ++i)
#pragma unroll
        for (int j = 0; j < 4; ++j) {
            const int cc = col0 + wc + j * 16 + l15;
            if (EPI <= 1) {
                if (cc < Nvalid) {
#pragma unroll
                    for (int q = 0; q < 4; ++q) {
                        const size_t o = (size_t)(row0 + wr + i * 16 + rbase + q) * ldc + cc;
                        if (EPI == 1) ((short*)C0)[o] = f2bf(acc[i][j][q]);
                        else          ((float*)C0)[o] = acc[i][j][q];
                    }
                }
            } else if (EPI == 2) {
                const int hh = cc / 192, d = cc - hh * 192;
#pragma unroll
                for (int q = 0; q < 4; ++q) {
                    const int row = row0 + wr + i * 16 + rbase + q;
                    const int s = row & 4095, b = row >> 12;
                    const float v = acc[i][j][q];
                    const float pv = __shfl_xor(v, 1, 64);
                    float val;
                    if (d >= 128) {
                        const int p = (d - 128) >> 1;
                        const float c = cosT[(size_t)s * 32 + p];
                        const float si = sinT[(size_t)s * 32 + p];
                        val = ((d & 1) == 0) ? (v * c - pv * si) : (pv * si + v * c);
                    } else val = v;
                    ((short*)C0)[((size_t)(b * 16 + hh) * 4096 + s) * 192 + d] = f2bf(elu1(val));
                }
            } else {  // EPI == 3
                const int hh = cc >> 8, d = cc & 255;
#pragma unroll
                for (int q = 0; q < 4; ++q) {
                    const int row = row0 + wr + i * 16 + rbase + q;
                    const int s = row & 4095, b = row >> 12;
                    const float v = acc[i][j][q];
                    if (d < 128)
                        ((short*)C0)[((size_t)(b * 16 + hh) * 4096 + s) * 192 + d] = f2bf(elu1(v));
                    else
                        ((short*)C1)[((size_t)(b * 16 + hh) * 4096 + s) * 128 + d - 128] = f2bf(v);
                }
            }
        }
}

// ---------- RMSNorm (q-lat, kv-lat) + RoPE+ELU on k_pe (bf16 out) ----------
__global__ __launch_bounds__(256) void rms_rope(
    const short* __restrict__ Y1,
    const float* __restrict__ qw, const float* __restrict__ kvw,
    const float* __restrict__ cosT, const float* __restrict__ sinT,
    short* __restrict__ qn, short* __restrict__ kvn, short* __restrict__ kpe)
{
    __shared__ float red[256];
    const int row = blockIdx.x;
    const int s = row & 4095;
    const int t = threadIdx.x;
    const unsigned short* yr = (const unsigned short*)(Y1 + (size_t)row * 1088);

    float v0 = bf2f(yr[t]), v1 = bf2f(yr[t + 256]);
    red[t] = v0 * v0 + v1 * v1;
    __syncthreads();
    for (int off = 128; off > 0; off >>= 1) {
        if (t < off) red[t] += red[t + off];
        __syncthreads();
    }
    float rs = rsqrtf(red[0] / 512.f + 1e-6f);
    __syncthreads();
    qn[(size_t)row * 512 + t]       = f2bf(v0 * rs * qw[t]);
    qn[(size_t)row * 512 + t + 256] = f2bf(v1 * rs * qw[t + 256]);

    float u0 = bf2f(yr[512 + t]), u1 = bf2f(yr[768 + t]);
    red[t] = u0 * u0 + u1 * u1;
    __syncthreads();
    for (int off = 128; off > 0; off >>= 1) {
        if (t < off) red[t] += red[t + off];
        __syncthreads();
    }
    float rs2 = rsqrtf(red[0] / 512.f + 1e-6f);
    kvn[(size_t)row * 512 + t]       = f2bf(u0 * rs2 * kvw[t]);
    kvn[(size_t)row * 512 + t + 256] = f2bf(u1 * rs2 * kvw[t + 256]);

    if (t < 32) {
        float xr = bf2f(yr[1024 + 2 * t]), xi = bf2f(yr[1024 + 2 * t + 1]);
        float cc = cosT[(size_t)s * 32 + t], sn = sinT[(size_t)s * 32 + t];
        kpe[(size_t)row * 64 + 2 * t]     = f2bf(elu1(xr * cc - xi * sn));
        kpe[(size_t)row * 64 + 2 * t + 1] = f2bf(elu1(xr * sn + xi * cc));
    }
}

// ---------- broadcast roped+elu'd k_pe into k_ssa[...,128:192] for all heads ----------
__global__ __launch_bounds__(256) void build_kpe(
    const short* __restrict__ kpe, short* __restrict__ k_ssa)
{
    const int row = blockIdx.x;
    const int s = row & 4095, b = row >> 12;
    const int t = threadIdx.x;
    const short* pe = kpe + (size_t)row * 64;
#pragma unroll
    for (int it = 0; it < 4; ++it) {
        const int idx = t + it * 256;
        const int h = idx >> 6, dd = idx & 63;
        k_ssa[((size_t)(b * 16 + h) * 4096 + s) * 192 + 128 + dd] = pe[dd];
    }
}

// ---------- transpose init_state [bh][dk][dv] -> [bh][dv][dk] ----------
__global__ __launch_bounds__(256) void init_t_kern(
    const float* __restrict__ init, float* __restrict__ initT)
{
    __shared__ float tile[32][33];
    const int bh = blockIdx.y;
    const int tk = blockIdx.x % 6, tv = blockIdx.x / 6;
    const int r0 = threadIdx.x >> 5, c = threadIdx.x & 31;
    const float* src = init + (size_t)bh * 24576;
    float* dst = initT + (size_t)bh * 24576;
#pragma unroll
    for (int p = 0; p < 4; ++p) {
        const int rr = r0 + 8 * p;
        tile[rr][c] = src[(size_t)(tk * 32 + rr) * 128 + tv * 32 + c];
    }
    __syncthreads();
#pragma unroll
    for (int p = 0; p < 4; ++p) {
        const int rr = r0 + 8 * p;
        dst[(size_t)(tv * 32 + rr) * 192 + tk * 32 + c] = tile[c][rr];
    }
}

// ---------- per-chunk kv^T = V^T K, bf16 transposed output [dv][dk] ----------
__global__ __launch_bounds__(256, 3) void ssa_kv(
    const short* __restrict__ k_ssa, const short* __restrict__ v_ssa,
    short* __restrict__ kvcT)
{
    __shared__ short smem[25600];                    // 51200 B
    short (*lkt)[72] = (short(*)[72])smem;           // [192][72]
    short (*lvt)[72] = (short(*)[72])(smem + 192 * 72);  // [128][72]
    short (*outT)[200] = (short(*)[200])smem;        // [128][200] (alias)
    const int c = blockIdx.x, h = blockIdx.y, b = blockIdx.z;
    const int bh = b * 16 + h;
    const short* Kc = k_ssa + ((size_t)bh * 4096 + c * 64) * 192;
    const short* Vc = v_ssa + ((size_t)bh * 4096 + c * 64) * 128;
    const int t = threadIdx.x, lane = t & 63, w = t >> 6;
    const int l15 = lane & 15, kg = (lane >> 4) * 8, rbase = (lane >> 4) * 4;

    for (int i = t; i < 64 * 48; i += 256) {
        const int row = i / 48, c4 = (i % 48) * 4;
        ushort4 kv4 = *(const ushort4*)(Kc + (size_t)row * 192 + c4);
        lkt[c4 + 0][row] = (short)kv4.x;
        lkt[c4 + 1][row] = (short)kv4.y;
        lkt[c4 + 2][row] = (short)kv4.z;
        lkt[c4 + 3][row] = (short)kv4.w;
    }
    for (int i = t; i < 64 * 32; i += 256) {
        const int row = i >> 5, c4 = (i & 31) * 4;
        ushort4 vv = *(const ushort4*)(Vc + (size_t)row * 128 + c4);
        lvt[c4 + 0][row] = (short)vv.x;
        lvt[c4 + 1][row] = (short)vv.y;
        lvt[c4 + 2][row] = (short)vv.z;
        lvt[c4 + 3][row] = (short)vv.w;
    }
    __syncthreads();

    f32x4 acc[2][12];
#pragma unroll
    for (int i = 0; i < 2; ++i)
#pragma unroll
        for (int j = 0; j < 12; ++j) acc[i][j] = (f32x4){0.f, 0.f, 0.f, 0.f};
#pragma unroll
    for (int ks = 0; ks < 2; ++ks) {
        bf16x8 af[2];
#pragma unroll
        for (int i = 0; i < 2; ++i) af[i] = *(const bf16x8*)&lvt[w * 32 + i * 16 + l15][ks * 32 + kg];
#pragma unroll
        for (int j = 0; j < 12; ++j) {
            const bf16x8 bk = *(const bf16x8*)&lkt[j * 16 + l15][ks * 32 + kg];
#pragma unroll
            for (int i = 0; i < 2; ++i) acc[i][j] = MFMA16(af[i], bk, acc[i][j]);
        }
    }
    __syncthreads();
#pragma unroll
    for (int i = 0; i < 2; ++i)
#pragma unroll
        for (int j = 0; j < 12; ++j)
#pragma unroll
            for (int q = 0; q < 4; ++q)
                outT[w * 32 + i * 16 + rbase + q][j * 16 + l15] = f2bf(acc[i][j][q]);
    __syncthreads();

    short* kvp = kvcT + ((size_t)bh * 64 + c) * 24576;
    for (int i = t; i < 3072; i += 256) {
        const int s8 = i * 8;
        const int row = s8 / 192, col = s8 % 192;
        *(u16x8*)(kvp + s8) = *(const u16x8*)&outT[row][col];
    }
}

// ---------- exclusive cumsum over chunks (bf16 in-place) + initT ----------
__global__ __launch_bounds__(256) void ssa_scan(
    short* __restrict__ kvc, const float* __restrict__ initT)
{
    const int bh = blockIdx.y;
    const int e8 = (blockIdx.x * 256 + threadIdx.x) * 8;
    float st[8];
    {
        const float4 i0 = *(const float4*)(initT + (size_t)bh * 24576 + e8);
        const float4 i1 = *(const float4*)(initT + (size_t)bh * 24576 + e8 + 4);
        st[0] = i0.x; st[1] = i0.y; st[2] = i0.z; st[3] = i0.w;
        st[4] = i1.x; st[5] = i1.y; st[6] = i1.z; st[7] = i1.w;
    }
    short* p = kvc + (size_t)bh * 64 * 24576 + e8;
    for (int cc = 0; cc < 64; ++cc) {
        const u16x8 v = *(const u16x8*)p;
        u16x8 o;
#pragma unroll
        for (int j = 0; j < 8; ++j) o[j] = (unsigned short)f2bf(st[j]);
        *(u16x8*)p = o;
#pragma unroll
        for (int j = 0; j < 8; ++j) st[j] += bf2f(v[j]);
        p += 24576;
    }
}

// ---------- fused: sc=tril(QK^T); attn=(sc@V + Q@state)*SCALE ----------
__global__ __launch_bounds__(256, 2) void ssa_out(
    const short* __restrict__ q_ssa, const short* __restrict__ k_ssa,
    const short* __restrict__ v_ssa, const short* __restrict__ states,
    short* __restrict__ attnb)
{
    __shared__ short lk[64][200];
    __shared__ short lvt[128][72];
    __shared__ short lst[128][104];
    __shared__ short lsc[64][72];
    const int c = blockIdx.x, h = blockIdx.y, b = blockIdx.z;
    const int bh = b * 16 + h;
    const short* Qb = q_ssa + ((size_t)bh * 4096 + c * 64) * 192;
    const short* Kc = k_ssa + ((size_t)bh * 4096 + c * 64) * 192;
    const short* Vc = v_ssa + ((size_t)bh * 4096 + c * 64) * 128;
    const short* st = states + ((size_t)bh * 64 + c) * 24576;
    const int t = threadIdx.x, lane = t & 63, w = t >> 6;
    const int l15 = lane & 15, kg = (lane >> 4) * 8, rbase = (lane >> 4) * 4;

    bf16x8 aq[6];
    {
        const short* Qr = Qb + (size_t)(w * 16 + l15) * 192 + kg;
#pragma unroll
        for (int ks = 0; ks < 6; ++ks) aq[ks] = *(const bf16x8*)(Qr + ks * 32);
    }
    for (int i = t; i < 1536; i += 256) {
        const int row = i / 24, c8 = (i % 24) * 8;
        *(u16x8*)&lk[row][c8] = *(const u16x8*)(Kc + (size_t)row * 192 + c8);
    }
    for (int i = t; i < 2048; i += 256) {
        const int row = i >> 5, c4 = (i & 31) * 4;
        ushort4 vv = *(const ushort4*)(Vc + (size_t)row * 128 + c4);
        lvt[c4 + 0][row] = (short)vv.x;
        lvt[c4 + 1][row] = (short)vv.y;
        lvt[c4 + 2][row] = (short)vv.z;
        lvt[c4 + 3][row] = (short)vv.w;
    }
    for (int i = t; i < 1536; i += 256) {
        const int row = i / 12, c8 = (i % 12) * 8;
        *(u16x8*)&lst[row][c8] = *(const u16x8*)(st + (size_t)row * 192 + c8);
    }
    __syncthreads();

    {
        f32x4 sc[4];
#pragma unroll
        for (int j = 0; j < 4; ++j) sc[j] = (f32x4){0.f, 0.f, 0.f, 0.f};
#pragma unroll
        for (int ks = 0; ks < 6; ++ks)
#pragma unroll
            for (int j = 0; j < 4; ++j) {
                const bf16x8 bk = *(const bf16x8*)&lk[j * 16 + l15][ks * 32 + kg];
                sc[j] = MFMA16(aq[ks], bk, sc[j]);
            }
#pragma unroll
        for (int j = 0; j < 4; ++j)
#pragma unroll
            for (int q = 0; q < 4; ++q) {
                const int l = w * 16 + rbase + q;
                const int m = j * 16 + l15;
                lsc[l][m] = f2bf((m <= l) ? sc[j][q] : 0.f);
            }
    }
    __syncthreads();

    f32x4 acc[8];
#pragma unroll
    for (int j = 0; j < 8; ++j) acc[j] = (f32x4){0.f, 0.f, 0.f, 0.f};
#pragma unroll
    for (int ks = 0; ks < 2; ++ks) {
        const bf16x8 as = *(const bf16x8*)&lsc[w * 16 + l15][ks * 32 + kg];
#pragma unroll
        for (int j = 0; j < 8; ++j) {
            const bf16x8 bv = *(const bf16x8*)&lvt[j * 16 + l15][ks * 32 + kg];
            acc[j] = MFMA16(as, bv, acc[j]);
        }
    }
#pragma unroll
    for (int ks = 0; ks < 3; ++ks)
#pragma unroll
        for (int j = 0; j < 8; ++j) {
            const bf16x8 bs = *(const bf16x8*)&lst[j * 16 + l15][ks * 32 + kg];
            acc[j] = MFMA16(aq[ks], bs, acc[j]);
        }
    __syncthreads();
    for (int i = t; i < 1536; i += 256) {
        const int row = i / 12, c8 = (i % 12) * 8;
        *(u16x8*)&lst[row][c8] = *(const u16x8*)(st + (size_t)row * 192 + 96 + c8);
    }
    __syncthreads();
#pragma unroll
    for (int ks = 3; ks < 6; ++ks)
#pragma unroll
        for (int j = 0; j < 8; ++j) {
            const bf16x8 bs = *(const bf16x8*)&lst[j * 16 + l15][(ks - 3) * 32 + kg];
            acc[j] = MFMA16(aq[ks], bs, acc[j]);
        }

    const float scale = 0.07216878364870322f;  // 192^-0.5
#pragma unroll
    for (int j = 0; j < 8; ++j)
#pragma unroll
        for (int q = 0; q < 4; ++q) {
            const int l = w * 16 + rbase + q;
            const int dv = j * 16 + l15;
            attnb[((size_t)(b * 4096 + c * 64 + l)) * 2048 + h * 128 + dv] = f2bf(acc[j][q] * scale);
        }
}

// ---------- launch ----------
extern "C" void kernel_launch(void* const* d_in, const int* in_sizes, int n_in,
                              void* d_out, int out_size, void* d_ws, size_t ws_size,
                              hipStream_t stream) {
    const float* x     = (const float*)d_in[0];
    const float* cosT  = (const float*)d_in[2];
    const float* sinT  = (const float*)d_in[3];
    const float* wq_a  = (const float*)d_in[4];
    const float* wq_b  = (const float*)d_in[5];
    const float* wkv_a = (const float*)d_in[6];
    const float* wkv_b = (const float*)d_in[7];
    const float* wo    = (const float*)d_in[8];
    const float* qw    = (const float*)d_in[9];
    const float* kvw   = (const float*)d_in[10];
    const float* init  = (const float*)d_in[11];
    float* out = (float*)d_out;

    void* base = nullptr;
    hipGetSymbolAddress(&base, HIP_SYMBOL(g_ws));
    char* ws = (char*)base;
    size_t off = 0;
    auto take = [&](size_t bytes) -> char* {
        char* p = ws + off;
        off += (bytes + 255) & ~(size_t)255;
        return p;
    };
    short* xb    = (short*)take((size_t)8192 * 2048 * 2);
    short* wab   = (short*)take((size_t)1280 * 2048 * 2);   // [wq_a;wkv_a;pad to 1280]
    short* wqbb  = (short*)take((size_t)3072 * 512 * 2);
    short* wkvbb = (short*)take((size_t)4096 * 512 * 2);
    short* wob   = (short*)take((size_t)2048 * 2048 * 2);
    short* y1b   = (short*)take((size_t)8192 * 1088 * 2);
    short* qnb   = (short*)take((size_t)8192 * 512 * 2);
    short* kvnb  = (short*)take((size_t)8192 * 512 * 2);
    short* kpe   = (short*)take((size_t)8192 * 64 * 2);
    short* qs    = (short*)take((size_t)2 * 16 * 4096 * 192 * 2);
    short* ksb   = (short*)take((size_t)2 * 16 * 4096 * 192 * 2);
    short* vsb   = (short*)take((size_t)2 * 16 * 4096 * 128 * 2);
    short* kvcT  = (short*)take((size_t)2048 * 24576 * 2);
    float* initT = (float*)take((size_t)32 * 24576 * 4);
    short* attnb = (short*)take((size_t)8192 * 2048 * 2);

    // 0. convert inputs/weights to bf16; transpose init
    cvt_bf16<<<(8192 * 2048 / 4 + 255) / 256, 256, 0, stream>>>(x, xb, 8192 * 2048);
    cvt_bf16<<<(512 * 2048 / 4 + 255) / 256, 256, 0, stream>>>(wq_a, wab, 512 * 2048);
    cvt_bf16<<<(576 * 2048 / 4 + 255) / 256, 256, 0, stream>>>(wkv_a, wab + (size_t)512 * 2048, 576 * 2048);
    hipMemsetAsync(wab + (size_t)1088 * 2048, 0, (size_t)192 * 2048 * 2, stream);
    cvt_bf16<<<(3072 * 512 / 4 + 255) / 256, 256, 0, stream>>>(wq_b, wqbb, 3072 * 512);
    cvt_bf16<<<(4096 * 512 / 4 + 255) / 256, 256, 0, stream>>>(wkv_b, wkvbb, 4096 * 512);
    cvt_bf16<<<(2048 * 2048 / 4 + 255) / 256, 256, 0, stream>>>(wo, wob, 2048 * 2048);
    init_t_kern<<<dim3(24, 32), 256, 0, stream>>>(init, initT);

    // 1. Y1 = x @ [wq_a; wkv_a]^T   (Npad=1280, Nvalid=1088)
    gemm_bn<1><<<320, 512, 0, stream>>>(xb, 2048, wab, 2048, y1b, nullptr, 1088, 1088, 2048, 10, nullptr, nullptr);
    // 2. RMSNorm + rope(k_pe)+elu
    rms_rope<<<8192, 256, 0, stream>>>(y1b, qw, kvw, cosT, sinT, qnb, kvnb, kpe);
    // 3a. q = qn @ wq_b^T  -> fused rope+elu+relayout into qs
    gemm_bn<2><<<768, 512, 0, stream>>>(qnb, 512, wqbb, 512, qs, nullptr, 0, 3072, 512, 24, cosT, sinT);
    // 3b. kv = kvn @ wkv_b^T -> fused elu K / V split
    gemm_bn<3><<<1024, 512, 0, stream>>>(kvnb, 512, wkvbb, 512, ksb, vsb, 0, 4096, 512, 32, nullptr, nullptr);
    build_kpe<<<8192, 256, 0, stream>>>(kpe, ksb);
    // 4. SSA
    ssa_kv<<<dim3(64, 16, 2), 256, 0, stream>>>(ksb, vsb, kvcT);
    ssa_scan<<<dim3(12, 32), 256, 0, stream>>>(kvcT, initT);
    ssa_out<<<dim3(64, 16, 2), 256, 0, stream>>>(qs, ksb, vsb, kvcT, attnb);
    // 5. out = attn @ wo^T (fp32 out)
    gemm_bn<0><<<512, 512, 0, stream>>>(attnb, 2048, wob, 2048, out, nullptr, 2048, 2048, 2048, 16, nullptr, nullptr);
}

// Round 8
// 610.880 us; speedup vs baseline: 1.0613x; 1.0613x over previous
//
#include <hip/hip_runtime.h>

// ---------- static device workspace ----------
static __device__ __align__(256) unsigned char g_ws[645200000];

// ---------- types ----------
typedef __attribute__((ext_vector_type(8))) __bf16 bf16x8;
typedef __attribute__((ext_vector_type(4))) float  f32x4;
typedef __attribute__((ext_vector_type(8))) unsigned short u16x8;

__device__ __forceinline__ short f2bf(float f) {
    union { float f; unsigned u; } v; v.f = f;
    unsigned r = v.u + 0x7FFFu + ((v.u >> 16) & 1u);
    return (short)(r >> 16);
}
__device__ __forceinline__ float bf2f(unsigned short u) {
    union { unsigned u; float f; } v; v.u = ((unsigned)u) << 16;
    return v.f;
}
__device__ __forceinline__ float elu1(float x) {
    return x > 0.f ? x + 1.f : __expf(x);
}
__device__ __forceinline__ void gload_lds16(const void* g, void* l) {
    __builtin_amdgcn_global_load_lds(
        (const __attribute__((address_space(1))) unsigned int*)g,
        (__attribute__((address_space(3))) unsigned int*)l, 16, 0, 0);
}

#define MFMA16(a, b, c) __builtin_amdgcn_mfma_f32_16x16x32_bf16((a), (b), (c), 0, 0, 0)

// ---------- fp32 -> bf16 convert ----------
__global__ __launch_bounds__(256) void cvt_bf16(
    const float* __restrict__ src, short* __restrict__ dst, int n)
{
    const int i = (blockIdx.x * 256 + threadIdx.x) * 4;
    if (i < n) {
        const float4 v = *(const float4*)(src + i);
        ushort4 o;
        o.x = (unsigned short)f2bf(v.x);
        o.y = (unsigned short)f2bf(v.y);
        o.z = (unsigned short)f2bf(v.z);
        o.w = (unsigned short)f2bf(v.w);
        *(ushort4*)(dst + i) = o;
    }
}

// ---------- GEMM 256x256, BK=32, 4-slot, counted vmcnt, conflict-free swizzle ----------
// C = A(bf16[M][lda]) @ Bt(bf16[Npad][ldb])^T.  512 thr (8 waves 2Mx4N).
// grid = (M/256)*(Npad/256); row-major tiles within XCD chunk: col=id%nby,row=id/nby.
// K mult of 32.  LDS rows 64B; lds[row][c16] holds global[row][c16 ^ ((row>>1)&3)];
// read XOR = ((l15>>1)&3)<<4  -> 2-way bank aliasing (free).
// EPI: 0=f32 plain, 1=bf16 plain, 2=q-mode (rope+elu), 3=kv-mode (elu K / V split)
template <int EPI>
__global__ __launch_bounds__(512, 1) void gemm256(
    const short* __restrict__ A, int lda,
    const short* __restrict__ Bt, int ldb,
    void* __restrict__ C0, void* __restrict__ C1, int ldc,
    int Nvalid, int K, int nby,
    const float* __restrict__ cosT, const float* __restrict__ sinT)
{
    __shared__ char lds[131072];   // A: 4 slots x 16K at 0; B: 4 slots x 16K at 65536
    const int t = threadIdx.x;
    const int lane = t & 63, w = t >> 6;

    const int cpx = gridDim.x >> 3;
    const int id = ((int)blockIdx.x & 7) * cpx + ((int)blockIdx.x >> 3);
    const int col0 = (id % nby) * 256;
    const int row0 = (id / nby) * 256;

    // staging: wave w rows [w*32, w*32+32), 2 issues of 16 rows; 64B per row.
    const int r_in = lane >> 2;                                    // 0..15
    const int srcb = (((lane & 3) ^ ((lane >> 3) & 3)) << 4);      // pre-permuted source
    const char* aSrc = (const char*)A + ((size_t)(row0 + w * 32 + r_in) * lda) * 2 + srcb;
    const char* bSrc = (const char*)Bt + ((size_t)(col0 + w * 32 + r_in) * ldb) * 2 + srcb;
    const size_t aRow16 = (size_t)lda * 32;                        // 16 rows in bytes
    const size_t bRow16 = (size_t)ldb * 32;
    char* aD = lds + w * 2048 + lane * 16;
    char* bD = lds + 65536 + w * 2048 + lane * 16;

    // compute: wave grid 2(M)x4(N); per-wave 128x64 out
    const int wr = (w >> 2) * 128, wc = (w & 3) * 64;
    const int l15 = lane & 15;
    const int g16 = (lane >> 4) << 4;            // 16B chunk byte offset
    const int rxor = ((l15 >> 1) & 3) << 4;      // row-dependent XOR (bits 1-2!)

    const int NT = K >> 5;

    auto STAGE = [&](int j) {
        const int sl = (j & 3) * 16384;
        const size_t kb = (size_t)j * 64;
        gload_lds16(aSrc + kb,          aD + sl);
        gload_lds16(aSrc + kb + aRow16, aD + sl + 1024);
        gload_lds16(bSrc + kb,          bD + sl);
        gload_lds16(bSrc + kb + bRow16, bD + sl + 1024);
    };

    f32x4 acc[8][4];
#pragma unroll
    for (int i = 0; i < 8; ++i)
#pragma unroll
        for (int j = 0; j < 4; ++j) acc[i][j] = (f32x4){0.f, 0.f, 0.f, 0.f};

    STAGE(0); STAGE(1); STAGE(2);

#pragma unroll 1
    for (int kt = 0; kt < NT; ++kt) {
        if (kt < NT - 2)        asm volatile("s_waitcnt vmcnt(8)" ::: "memory");
        else if (kt == NT - 2)  asm volatile("s_waitcnt vmcnt(4)" ::: "memory");
        else                    asm volatile("s_waitcnt vmcnt(0)" ::: "memory");
        __builtin_amdgcn_sched_barrier(0);
        __builtin_amdgcn_s_barrier();
        if (kt + 3 < NT) STAGE(kt + 3);
        const char* aS = lds + (kt & 3) * 16384;
        const char* bS = lds + 65536 + (kt & 3) * 16384;
        bf16x8 af[8], bf4[4];
#pragma unroll
        for (int i = 0; i < 8; ++i)
            af[i] = *(const bf16x8*)(aS + (wr + i * 16 + l15) * 64 + (g16 ^ rxor));
#pragma unroll
        for (int j = 0; j < 4; ++j)
            bf4[j] = *(const bf16x8*)(bS + (wc + j * 16 + l15) * 64 + (g16 ^ rxor));
        __builtin_amdgcn_s_setprio(1);
#pragma unroll
        for (int i = 0; i < 8; ++i)
#pragma unroll
            for (int j = 0; j < 4; ++j)
                acc[i][j] = MFMA16(af[i], bf4[j], acc[i][j]);
        __builtin_amdgcn_s_setprio(0);
    }

    const int rbase = (lane >> 4) * 4;
#pragma unroll
    for (int i = 0; i < 8; ++i)
#pragma unroll
        for (int j = 0; j < 4; ++j) {
            const int cc = col0 + wc + j * 16 + l15;
            if (EPI <= 1) {
                if (cc < Nvalid) {
#pragma unroll
                    for (int q = 0; q < 4; ++q) {
                        const size_t o = (size_t)(row0 + wr + i * 16 + rbase + q) * ldc + cc;
                        if (EPI == 1) ((short*)C0)[o] = f2bf(acc[i][j][q]);
                        else          ((float*)C0)[o] = acc[i][j][q];
                    }
                }
            } else if (EPI == 2) {
                const int hh = cc / 192, d = cc - hh * 192;
#pragma unroll
                for (int q = 0; q < 4; ++q) {
                    const int row = row0 + wr + i * 16 + rbase + q;
                    const int s = row & 4095, b = row >> 12;
                    const float v = acc[i][j][q];
                    const float pv = __shfl_xor(v, 1, 64);
                    float val;
                    if (d >= 128) {
                        const int p = (d - 128) >> 1;
                        const float c = cosT[(size_t)s * 32 + p];
                        const float si = sinT[(size_t)s * 32 + p];
                        val = ((d & 1) == 0) ? (v * c - pv * si) : (pv * si + v * c);
                    } else val = v;
                    ((short*)C0)[((size_t)(b * 16 + hh) * 4096 + s) * 192 + d] = f2bf(elu1(val));
                }
            } else {  // EPI == 3
                const int hh = cc >> 8, d = cc & 255;
#pragma unroll
                for (int q = 0; q < 4; ++q) {
                    const int row = row0 + wr + i * 16 + rbase + q;
                    const int s = row & 4095, b = row >> 12;
                    const float v = acc[i][j][q];
                    if (d < 128)
                        ((short*)C0)[((size_t)(b * 16 + hh) * 4096 + s) * 192 + d] = f2bf(elu1(v));
                    else
                        ((short*)C1)[((size_t)(b * 16 + hh) * 4096 + s) * 128 + d - 128] = f2bf(v);
                }
            }
        }
}

// ---------- RMSNorm (q-lat, kv-lat) + RoPE+ELU on k_pe; shuffle reduce ----------
__global__ __launch_bounds__(256) void rms_rope(
    const short* __restrict__ Y1,
    const float* __restrict__ qw, const float* __restrict__ kvw,
    const float* __restrict__ cosT, const float* __restrict__ sinT,
    short* __restrict__ qn, short* __restrict__ kvn, short* __restrict__ kpe)
{
    __shared__ float wsq[4], wsk[4];
    const int row = blockIdx.x;
    const int s = row & 4095;
    const int t = threadIdx.x;
    const int w = t >> 6, lane = t & 63;
    const unsigned short* yr = (const unsigned short*)(Y1 + (size_t)row * 1088);

    const float v0 = bf2f(yr[t]),       v1 = bf2f(yr[t + 256]);
    const float u0 = bf2f(yr[512 + t]), u1 = bf2f(yr[768 + t]);
    float sq = v0 * v0 + v1 * v1;
    float sk = u0 * u0 + u1 * u1;
#pragma unroll
    for (int off = 32; off > 0; off >>= 1) {
        sq += __shfl_xor(sq, off, 64);
        sk += __shfl_xor(sk, off, 64);
    }
    if (lane == 0) { wsq[w] = sq; wsk[w] = sk; }
    __syncthreads();
    const float rs  = rsqrtf((wsq[0] + wsq[1] + wsq[2] + wsq[3]) / 512.f + 1e-6f);
    const float rs2 = rsqrtf((wsk[0] + wsk[1] + wsk[2] + wsk[3]) / 512.f + 1e-6f);

    qn[(size_t)row * 512 + t]        = f2bf(v0 * rs * qw[t]);
    qn[(size_t)row * 512 + t + 256]  = f2bf(v1 * rs * qw[t + 256]);
    kvn[(size_t)row * 512 + t]       = f2bf(u0 * rs2 * kvw[t]);
    kvn[(size_t)row * 512 + t + 256] = f2bf(u1 * rs2 * kvw[t + 256]);

    if (t < 32) {
        float xr = bf2f(yr[1024 + 2 * t]), xi = bf2f(yr[1024 + 2 * t + 1]);
        float cc = cosT[(size_t)s * 32 + t], sn = sinT[(size_t)s * 32 + t];
        kpe[(size_t)row * 64 + 2 * t]     = f2bf(elu1(xr * cc - xi * sn));
        kpe[(size_t)row * 64 + 2 * t + 1] = f2bf(elu1(xr * sn + xi * cc));
    }
}

// ---------- broadcast roped+elu'd k_pe into k_ssa[...,128:192] (16B stores) ----------
__global__ __launch_bounds__(128) void build_kpe(
    const short* __restrict__ kpe, short* __restrict__ k_ssa)
{
    const int row = blockIdx.x;
    const int s = row & 4095, b = row >> 12;
    const int t = threadIdx.x;          // 0..127
    const int h = t >> 3, d8 = (t & 7) * 8;
    const u16x8 v = *(const u16x8*)(kpe + (size_t)row * 64 + d8);
    *(u16x8*)(k_ssa + ((size_t)(b * 16 + h) * 4096 + s) * 192 + 128 + d8) = v;
}

// ---------- transpose init_state [bh][dk][dv] -> [bh][dv][dk] ----------
__global__ __launch_bounds__(256) void init_t_kern(
    const float* __restrict__ init, float* __restrict__ initT)
{
    __shared__ float tile[32][33];
    const int bh = blockIdx.y;
    const int tk = blockIdx.x % 6, tv = blockIdx.x / 6;
    const int r0 = threadIdx.x >> 5, c = threadIdx.x & 31;
    const float* src = init + (size_t)bh * 24576;
    float* dst = initT + (size_t)bh * 24576;
#pragma unroll
    for (int p = 0; p < 4; ++p) {
        const int rr = r0 + 8 * p;
        tile[rr][c] = src[(size_t)(tk * 32 + rr) * 128 + tv * 32 + c];
    }
    __syncthreads();
#pragma unroll
    for (int p = 0; p < 4; ++p) {
        const int rr = r0 + 8 * p;
        dst[(size_t)(tv * 32 + rr) * 192 + tk * 32 + c] = tile[c][rr];
    }
}

// ---------- per-chunk kv^T = V^T K, bf16 transposed output [dv][dk] ----------
__global__ __launch_bounds__(256, 3) void ssa_kv(
    const short* __restrict__ k_ssa, const short* __restrict__ v_ssa,
    short* __restrict__ kvcT)
{
    __shared__ short smem[25600];                    // 51200 B
    short (*lkt)[72] = (short(*)[72])smem;           // [192][72]
    short (*lvt)[72] = (short(*)[72])(smem + 192 * 72);  // [128][72]
    short (*outT)[200] = (short(*)[200])smem;        // [128][200] (alias)
    const int c = blockIdx.x, h = blockIdx.y, b = blockIdx.z;
    const int bh = b * 16 + h;
    const short* Kc = k_ssa + ((size_t)bh * 4096 + c * 64) * 192;
    const short* Vc = v_ssa + ((size_t)bh * 4096 + c * 64) * 128;
    const int t = threadIdx.x, lane = t & 63, w = t >> 6;
    const int l15 = lane & 15, kg = (lane >> 4) * 8, rbase = (lane >> 4) * 4;

    for (int i = t; i < 64 * 48; i += 256) {
        const int row = i / 48, c4 = (i % 48) * 4;
        ushort4 kv4 = *(const ushort4*)(Kc + (size_t)row * 192 + c4);
        lkt[c4 + 0][row] = (short)kv4.x;
        lkt[c4 + 1][row] = (short)kv4.y;
        lkt[c4 + 2][row] = (short)kv4.z;
        lkt[c4 + 3][row] = (short)kv4.w;
    }
    for (int i = t; i < 64 * 32; i += 256) {
        const int row = i >> 5, c4 = (i & 31) * 4;
        ushort4 vv = *(const ushort4*)(Vc + (size_t)row * 128 + c4);
        lvt[c4 + 0][row] = (short)vv.x;
        lvt[c4 + 1][row] = (short)vv.y;
        lvt[c4 + 2][row] = (short)vv.z;
        lvt[c4 + 3][row] = (short)vv.w;
    }
    __syncthreads();

    f32x4 acc[2][12];
#pragma unroll
    for (int i = 0; i < 2; ++i)
#pragma unroll
        for (int j = 0; j < 12; ++j) acc[i][j] = (f32x4){0.f, 0.f, 0.f, 0.f};
#pragma unroll
    for (int ks = 0; ks < 2; ++ks) {
        bf16x8 af[2];
#pragma unroll
        for (int i = 0; i < 2; ++i) af[i] = *(const bf16x8*)&lvt[w * 32 + i * 16 + l15][ks * 32 + kg];
#pragma unroll
        for (int j = 0; j < 12; ++j) {
            const bf16x8 bk = *(const bf16x8*)&lkt[j * 16 + l15][ks * 32 + kg];
#pragma unroll
            for (int i = 0; i < 2; ++i) acc[i][j] = MFMA16(af[i], bk, acc[i][j]);
        }
    }
    __syncthreads();
#pragma unroll
    for (int i = 0; i < 2; ++i)
#pragma unroll
        for (int j = 0; j < 12; ++j)
#pragma unroll
            for (int q = 0; q < 4; ++q)
                outT[w * 32 + i * 16 + rbase + q][j * 16 + l15] = f2bf(acc[i][j][q]);
    __syncthreads();

    short* kvp = kvcT + ((size_t)bh * 64 + c) * 24576;
    for (int i = t; i < 3072; i += 256) {
        const int s8 = i * 8;
        const int row = s8 / 192, col = s8 % 192;
        *(u16x8*)(kvp + s8) = *(const u16x8*)&outT[row][col];
    }
}

// ---------- exclusive cumsum over chunks (bf16 in-place) + initT ----------
// 1536 blocks: 2 elems/thread packed in one 4B word -> 6 blocks/CU of chains.
__global__ __launch_bounds__(256) void ssa_scan(
    short* __restrict__ kvc, const float* __restrict__ initT)
{
    const int bh = blockIdx.y;
    const int e2 = (blockIdx.x * 256 + threadIdx.x) * 2;
    const float2 iv = *(const float2*)(initT + (size_t)bh * 24576 + e2);
    float s0 = iv.x, s1 = iv.y;
    unsigned* p = (unsigned*)(kvc + (size_t)bh * 64 * 24576 + e2);
#pragma unroll 2
    for (int cc = 0; cc < 64; ++cc) {
        const unsigned v = *p;
        const unsigned o = (unsigned)(unsigned short)f2bf(s0) |
                           ((unsigned)(unsigned short)f2bf(s1) << 16);
        *p = o;
        s0 += bf2f((unsigned short)(v & 0xffffu));
        s1 += bf2f((unsigned short)(v >> 16));
        p += 12288;   // 24576 shorts = 12288 uints
    }
}

// ---------- fused: sc=tril(QK^T); attn=(sc@V + Q@state)*SCALE ----------
__global__ __launch_bounds__(256, 2) void ssa_out(
    const short* __restrict__ q_ssa, const short* __restrict__ k_ssa,
    const short* __restrict__ v_ssa, const short* __restrict__ states,
    short* __restrict__ attnb)
{
    __shared__ short lk[64][200];
    __shared__ short lvt[128][72];
    __shared__ short lst[128][104];
    __shared__ short lsc[64][72];
    const int c = blockIdx.x, h = blockIdx.y, b = blockIdx.z;
    const int bh = b * 16 + h;
    const short* Qb = q_ssa + ((size_t)bh * 4096 + c * 64) * 192;
    const short* Kc = k_ssa + ((size_t)bh * 4096 + c * 64) * 192;
    const short* Vc = v_ssa + ((size_t)bh * 4096 + c * 64) * 128;
    const short* st = states + ((size_t)bh * 64 + c) * 24576;
    const int t = threadIdx.x, lane = t & 63, w = t >> 6;
    const int l15 = lane & 15, kg = (lane >> 4) * 8, rbase = (lane >> 4) * 4;

    bf16x8 aq[6];
    {
        const short* Qr = Qb + (size_t)(w * 16 + l15) * 192 + kg;
#pragma unroll
        for (int ks = 0; ks < 6; ++ks) aq[ks] = *(const bf16x8*)(Qr + ks * 32);
    }
    for (int i = t; i < 1536; i += 256) {
        const int row = i / 24, c8 = (i % 24) * 8;
        *(u16x8*)&lk[row][c8] = *(const u16x8*)(Kc + (size_t)row * 192 + c8);
    }
    for (int i = t; i < 2048; i += 256) {
        const int row = i >> 5, c4 = (i & 31) * 4;
        ushort4 vv = *(const ushort4*)(Vc + (size_t)row * 128 + c4);
        lvt[c4 + 0][row] = (short)vv.x;
        lvt[c4 + 1][row] = (short)vv.y;
        lvt[c4 + 2][row] = (short)vv.z;
        lvt[c4 + 3][row] = (short)vv.w;
    }
    for (int i = t; i < 1536; i += 256) {
        const int row = i / 12, c8 = (i % 12) * 8;
        *(u16x8*)&lst[row][c8] = *(const u16x8*)(st + (size_t)row * 192 + c8);
    }
    __syncthreads();

    {
        f32x4 sc[4];
#pragma unroll
        for (int j = 0; j < 4; ++j) sc[j] = (f32x4){0.f, 0.f, 0.f, 0.f};
#pragma unroll
        for (int ks = 0; ks < 6; ++ks)
#pragma unroll
            for (int j = 0; j < 4; ++j) {
                const bf16x8 bk = *(const bf16x8*)&lk[j * 16 + l15][ks * 32 + kg];
                sc[j] = MFMA16(aq[ks], bk, sc[j]);
            }
#pragma unroll
        for (int j = 0; j < 4; ++j)
#pragma unroll
            for (int q = 0; q < 4; ++q) {
                const int l = w * 16 + rbase + q;
                const int m = j * 16 + l15;
                lsc[l][m] = f2bf((m <= l) ? sc[j][q] : 0.f);
            }
    }
    __syncthreads();

    f32x4 acc[8];
#pragma unroll
    for (int j = 0; j < 8; ++j) acc[j] = (f32x4){0.f, 0.f, 0.f, 0.f};
#pragma unroll
    for (int ks = 0; ks < 2; ++ks) {
        const bf16x8 as = *(const bf16x8*)&lsc[w * 16 + l15][ks * 32 + kg];
#pragma unroll
        for (int j = 0; j < 8; ++j) {
            const bf16x8 bv = *(const bf16x8*)&lvt[j * 16 + l15][ks * 32 + kg];
            acc[j] = MFMA16(as, bv, acc[j]);
        }
    }
#pragma unroll
    for (int ks = 0; ks < 3; ++ks)
#pragma unroll
        for (int j = 0; j < 8; ++j) {
            const bf16x8 bs = *(const bf16x8*)&lst[j * 16 + l15][ks * 32 + kg];
            acc[j] = MFMA16(aq[ks], bs, acc[j]);
        }
    __syncthreads();
    for (int i = t; i < 1536; i += 256) {
        const int row = i / 12, c8 = (i % 12) * 8;
        *(u16x8*)&lst[row][c8] = *(const u16x8*)(st + (size_t)row * 192 + 96 + c8);
    }
    __syncthreads();
#pragma unroll
    for (int ks = 3; ks < 6; ++ks)
#pragma unroll
        for (int j = 0; j < 8; ++j) {
            const bf16x8 bs = *(const bf16x8*)&lst[j * 16 + l15][(ks - 3) * 32 + kg];
            acc[j] = MFMA16(aq[ks], bs, acc[j]);
        }

    const float scale = 0.07216878364870322f;  // 192^-0.5
#pragma unroll
    for (int j = 0; j < 8; ++j)
#pragma unroll
        for (int q = 0; q < 4; ++q) {
            const int l = w * 16 + rbase + q;
            const int dv = j * 16 + l15;
            attnb[((size_t)(b * 4096 + c * 64 + l)) * 2048 + h * 128 + dv] = f2bf(acc[j][q] * scale);
        }
}

// ---------- launch ----------
extern "C" void kernel_launch(void* const* d_in, const int* in_sizes, int n_in,
                              void* d_out, int out_size, void* d_ws, size_t ws_size,
                              hipStream_t stream) {
    const float* x     = (const float*)d_in[0];
    const float* cosT  = (const float*)d_in[2];
    const float* sinT  = (const float*)d_in[3];
    const float* wq_a  = (const float*)d_in[4];
    const float* wq_b  = (const float*)d_in[5];
    const float* wkv_a = (const float*)d_in[6];
    const float* wkv_b = (const float*)d_in[7];
    const float* wo    = (const float*)d_in[8];
    const float* qw    = (const float*)d_in[9];
    const float* kvw   = (const float*)d_in[10];
    const float* init  = (const float*)d_in[11];
    float* out = (float*)d_out;

    void* base = nullptr;
    hipGetSymbolAddress(&base, HIP_SYMBOL(g_ws));
    char* ws = (char*)base;
    size_t off = 0;
    auto take = [&](size_t bytes) -> char* {
        char* p = ws + off;
        off += (bytes + 255) & ~(size_t)255;
        return p;
    };
    short* xb    = (short*)take((size_t)8192 * 2048 * 2);
    short* wab   = (short*)take((size_t)1280 * 2048 * 2);   // [wq_a;wkv_a;pad to 1280]
    short* wqbb  = (short*)take((size_t)3072 * 512 * 2);
    short* wkvbb = (short*)take((size_t)4096 * 512 * 2);
    short* wob   = (short*)take((size_t)2048 * 2048 * 2);
    short* y1b   = (short*)take((size_t)8192 * 1088 * 2);
    short* qnb   = (short*)take((size_t)8192 * 512 * 2);
    short* kvnb  = (short*)take((size_t)8192 * 512 * 2);
    short* kpe   = (short*)take((size_t)8192 * 64 * 2);
    short* qs    = (short*)take((size_t)2 * 16 * 4096 * 192 * 2);
    short* ksb   = (short*)take((size_t)2 * 16 * 4096 * 192 * 2);
    short* vsb   = (short*)take((size_t)2 * 16 * 4096 * 128 * 2);
    short* kvcT  = (short*)take((size_t)2048 * 24576 * 2);
    float* initT = (float*)take((size_t)32 * 24576 * 4);
    short* attnb = (short*)take((size_t)8192 * 2048 * 2);

    // 0. convert inputs/weights to bf16; transpose init
    cvt_bf16<<<(8192 * 2048 / 4 + 255) / 256, 256, 0, stream>>>(x, xb, 8192 * 2048);
    cvt_bf16<<<(512 * 2048 / 4 + 255) / 256, 256, 0, stream>>>(wq_a, wab, 512 * 2048);
    cvt_bf16<<<(576 * 2048 / 4 + 255) / 256, 256, 0, stream>>>(wkv_a, wab + (size_t)512 * 2048, 576 * 2048);
    hipMemsetAsync(wab + (size_t)1088 * 2048, 0, (size_t)192 * 2048 * 2, stream);
    cvt_bf16<<<(3072 * 512 / 4 + 255) / 256, 256, 0, stream>>>(wq_b, wqbb, 3072 * 512);
    cvt_bf16<<<(4096 * 512 / 4 + 255) / 256, 256, 0, stream>>>(wkv_b, wkvbb, 4096 * 512);
    cvt_bf16<<<(2048 * 2048 / 4 + 255) / 256, 256, 0, stream>>>(wo, wob, 2048 * 2048);
    init_t_kern<<<dim3(24, 32), 256, 0, stream>>>(init, initT);

    // 1. Y1 = x @ [wq_a; wkv_a]^T   (Npad=1280, Nvalid=1088)
    gemm256<1><<<160, 512, 0, stream>>>(xb, 2048, wab, 2048, y1b, nullptr, 1088, 1088, 2048, 5, nullptr, nullptr);
    // 2. RMSNorm + rope(k_pe)+elu
    rms_rope<<<8192, 256, 0, stream>>>(y1b, qw, kvw, cosT, sinT, qnb, kvnb, kpe);
    // 3a. q = qn @ wq_b^T  -> fused rope+elu+relayout into qs
    gemm256<2><<<384, 512, 0, stream>>>(qnb, 512, wqbb, 512, qs, nullptr, 0, 3072, 512, 12, cosT, sinT);
    // 3b. kv = kvn @ wkv_b^T -> fused elu K / V split
    gemm256<3><<<512, 512, 0, stream>>>(kvnb, 512, wkvbb, 512, ksb, vsb, 0, 4096, 512, 16, nullptr, nullptr);
    build_kpe<<<8192, 128, 0, stream>>>(kpe, ksb);
    // 4. SSA
    ssa_kv<<<dim3(64, 16, 2), 256, 0, stream>>>(ksb, vsb, kvcT);
    ssa_scan<<<dim3(48, 32), 256, 0, stream>>>(kvcT, initT);
    ssa_out<<<dim3(64, 16, 2), 256, 0, stream>>>(qs, ksb, vsb, kvcT, attnb);
    // 5. out = attn @ wo^T (fp32 out)
    gemm256<0><<<256, 512, 0, stream>>>(attnb, 2048, wob, 2048, out, nullptr, 2048, 2048, 2048, 8, nullptr, nullptr);
}